// Round 1
// baseline (597.407 us; speedup 1.0000x reference)
//
#include <hip/hip_runtime.h>

// NormXCorr: B=16, D=64, H=48, W=24, p=5, d=2, n=25, EPS=0.01
// out[b, d*120 + a*24 + c, x, y] = mean_k En[b,d,x,y,k] * Fn[b,d,x+a,c,k]
// En = normalized 5x5 X-patch at (x,y) (X padded 2 all sides)
// Fn = normalized 5x5 Y-patch at row x+a, col c (Y padded 4 vert, 2 horiz)
//
// Algebra: sum_k En_k = 0 exactly, so
//   ncc = (1/25) * invY * sum_k Xn_k * Y_k      (no mu_Y in inner loop)

#define BH 48
#define BW 24
constexpr float EPS = 0.01f;

__global__ __launch_bounds__(192, 3) void ncc_kernel(const float* __restrict__ X,
                                                     const float* __restrict__ Y,
                                                     float* __restrict__ out) {
    __shared__ float Xp[52 * 28];     // X padded +2 all sides
    __shared__ float Yp[56 * 28];     // Y padded +4 vert, +2 horiz
    __shared__ float invYs[52 * 24];  // 1/(sd+eps) for each Y patch position

    const int bd  = blockIdx.x;       // b*64 + d, 0..1023
    const int tid = threadIdx.x;      // 0..191

    const float* Xg = X + (size_t)bd * (BH * BW);
    const float* Yg = Y + (size_t)bd * (BH * BW);

    // ---- stage padded X slice into LDS ----
    for (int i = tid; i < 52 * 28; i += 192) {
        int r = i / 28, c = i % 28;
        int orr = r - 2, oc = c - 2;
        float v = 0.f;
        if (orr >= 0 && orr < BH && oc >= 0 && oc < BW) v = Xg[orr * BW + oc];
        Xp[i] = v;
    }
    // ---- stage padded Y slice into LDS ----
    for (int i = tid; i < 56 * 28; i += 192) {
        int r = i / 28, c = i % 28;
        int orr = r - 4, oc = c - 2;
        float v = 0.f;
        if (orr >= 0 && orr < BH && oc >= 0 && oc < BW) v = Yg[orr * BW + oc];
        Yp[i] = v;
    }
    __syncthreads();

    // ---- Y patch inverse-std for all 52x24 patch positions ----
    for (int i = tid; i < 52 * 24; i += 192) {
        int r = i / 24, c = i % 24;
        float s = 0.f, s2 = 0.f;
#pragma unroll
        for (int u = 0; u < 5; ++u)
#pragma unroll
            for (int v = 0; v < 5; ++v) {
                float val = Yp[(r + u) * 28 + (c + v)];
                s += val;
                s2 += val * val;
            }
        float mu  = s * 0.04f;
        float var = fmaxf(s2 * 0.04f - mu * mu, 0.f);
        invYs[i] = 1.f / (sqrtf(var) + EPS);
    }
    __syncthreads();

    // ---- main loop: thread = (x-octave, y); 6 x-iterations ----
    const int y  = tid % 24;   // X column
    const int xs = tid / 24;   // 0..7
    float* ob0 = out + (size_t)bd * (5 * 24 * 48 * 24);

    for (int xi = 0; xi < 6; ++xi) {
        const int x = xi * 8 + xs;  // 0..47

        // load + normalize X patch into registers (sum Xn == 0 afterwards)
        float xn[25];
        float s = 0.f, s2 = 0.f;
#pragma unroll
        for (int u = 0; u < 5; ++u)
#pragma unroll
            for (int v = 0; v < 5; ++v) {
                float val = Xp[(x + u) * 28 + (y + v)];
                xn[u * 5 + v] = val;
                s += val;
                s2 += val * val;
            }
        float mu  = s * 0.04f;
        float var = fmaxf(s2 * 0.04f - mu * mu, 0.f);
        float inv = 1.f / (sqrtf(var) + EPS);
#pragma unroll
        for (int k = 0; k < 25; ++k) xn[k] = (xn[k] - mu) * inv;

        // store base for this (x,y): lane-linear -> fully coalesced per wave
        float* ob = ob0 + x * 24 + y;

        for (int a = 0; a < 5; ++a) {
            const int yr = x + a;  // Y patch row (0..51)

            // ring-buffer sliding 5x5 Y window over c; slot s holds column
            // c' with c' % 5 == s. Full unroll -> pure register indexing.
            float w[25];
#pragma unroll
            for (int u = 0; u < 5; ++u)
#pragma unroll
                for (int sc = 0; sc < 5; ++sc)
                    w[u * 5 + sc] = Yp[(yr + u) * 28 + sc];

#pragma unroll
            for (int c = 0; c < 24; ++c) {
                float dot = 0.f;
#pragma unroll
                for (int u = 0; u < 5; ++u)
#pragma unroll
                    for (int v = 0; v < 5; ++v)
                        dot += xn[u * 5 + v] * w[u * 5 + ((c + v) % 5)];
                ob[(size_t)(a * 24 + c) * (48 * 24)] =
                    dot * invYs[yr * 24 + c] * 0.04f;
                if (c < 23) {
                    // load column c+5 into slot (c+5)%5 == c%5 (broadcast read)
#pragma unroll
                    for (int u = 0; u < 5; ++u)
                        w[u * 5 + (c % 5)] = Yp[(yr + u) * 28 + (c + 5)];
                }
            }
        }
    }
}

extern "C" void kernel_launch(void* const* d_in, const int* in_sizes, int n_in,
                              void* d_out, int out_size, void* d_ws, size_t ws_size,
                              hipStream_t stream) {
    const float* X = (const float*)d_in[0];
    const float* Y = (const float*)d_in[1];
    float* out = (float*)d_out;
    // d_in[2] is patch_size == 5, hardcoded above.
    ncc_kernel<<<dim3(1024), dim3(192), 0, stream>>>(X, Y, out);
}